// Round 6
// baseline (1578.995 us; speedup 1.0000x reference)
//
#include <hip/hip_runtime.h>
#include <math.h>

// ---------------------------------------------------------------------------
// FeatureEncoder R24 = R19 skeleton + fixed LDS staging on L0-L3.
// R23 autopsy: staging was right, execution wrong -
//  (a) stride-2 tap reads -> even-banks-only 4-way conflict (9.4M/dispatch)
//  (b) 2-phase stage->barrier->compute left waves stalling in lockstep
//  (c) per-batch div/mod index math ~40% of FMA issue
// R24: even/odd de-interleaved LDS (stride-1 taps, RS=20 -> exact 2-way =
// free), double-buffer w/ single barrier (loads for k+1 issued before
// compute(k), ds_write after - T14), slot offsets precomputed once.
// L0 conv7 gets LDS staging too (22x22x3 tile, RS=24 = 2-way free, reflect
// resolved at stage time; 147 VMEM taps/thread -> ~6).
// convT / L7 / seg / arena / grids: unchanged R19.
// ---------------------------------------------------------------------------

#define IDIV(a, b) (((a) + (b) - 1) / (b))

__device__ __forceinline__ int reflect_i(int i, int n) {
    i = i < 0 ? -i : i;
    return i >= n ? 2 * n - 2 - i : i;
}

__device__ __forceinline__ float ldb(const char* base, int boff) {
    return *(const float*)(base + boff);
}

// block-level (sum,sumsq) reduction for OCPT channels -> partial store
template <int OCPT>
__device__ __forceinline__ void stats_block_store(
    const float* sv, const float* ssv, float* __restrict__ spart,
    float* __restrict__ sspart, int P, int tile, int pc0) {
    __shared__ float redS[OCPT], redSS[OCPT];
    if (threadIdx.x < OCPT) { redS[threadIdx.x] = 0.f; redSS[threadIdx.x] = 0.f; }
    __syncthreads();
    int lane = threadIdx.x & 63;
#pragma unroll
    for (int j = 0; j < OCPT; ++j) {
        float s = sv[j], ss = ssv[j];
#pragma unroll
        for (int o = 32; o > 0; o >>= 1) {
            s += __shfl_down(s, o);
            ss += __shfl_down(ss, o);
        }
        if (lane == 0) { atomicAdd(&redS[j], s); atomicAdd(&redSS[j], ss); }  // LDS atomics
    }
    __syncthreads();
    if (threadIdx.x < OCPT) {
        spart[(size_t)tile * P + pc0 + threadIdx.x] = redS[threadIdx.x];
        sspart[(size_t)tile * P + pc0 + threadIdx.x] = redSS[threadIdx.x];
    }
}

// fold [nT][P] partials -> mean, inv (one wavefront per plane)
__global__ __launch_bounds__(64) void stat_reduce_mi(
    const float* __restrict__ sp, const float* __restrict__ ssp,
    float* __restrict__ mean, float* __restrict__ inv, int P, int nT,
    float rcp_plane) {
    int p = blockIdx.x;
    float a = 0.f, bsum = 0.f;
    for (int t = threadIdx.x; t < nT; t += 64) {
        a += sp[(size_t)t * P + p];
        bsum += ssp[(size_t)t * P + p];
    }
#pragma unroll
    for (int o = 32; o > 0; o >>= 1) {
        a += __shfl_down(a, o);
        bsum += __shfl_down(bsum, o);
    }
    if (threadIdx.x == 0) {
        float m = a * rcp_plane;
        float var = bsum * rcp_plane - m * m;
        mean[p] = m;
        inv[p] = rsqrtf(var + 1e-5f);
    }
}

// ---------------- 7x7 same-conv (L0), LDS-staged tile, fused stats ----------
// 16x16 outputs/block; staged window 22x22 per plane (reflect applied at
// stage). Row stride 24 -> tap reads exactly 2-way bank (free).
template <int CIN, int OCPT>
__global__ __launch_bounds__(256) void conv7_lds(
    const float* __restrict__ x, const float* __restrict__ w,
    const float* __restrict__ b, float* __restrict__ y,
    float* __restrict__ spart, float* __restrict__ sspart, int P,
    int Cout, int H, int W) {
    constexpr int TR = 22, TC = 22, RS = 24;
    __shared__ float s[CIN][TR][RS];
    int tx = threadIdx.x & 15, ty = threadIdx.x >> 4;
    int tilesX = W / 16;
    int bx = blockIdx.x % tilesX, by = blockIdx.x / tilesX;
    int oh0 = by * 16, ow0 = bx * 16;
    int oc0 = blockIdx.y * OCPT;
    int n = blockIdx.z;
    const float* xn = x + (size_t)n * CIN * H * W;

    for (int q = threadIdx.x; q < CIN * TR * TC; q += 256) {
        int p = q / (TR * TC), rem = q % (TR * TC);
        int r = rem / TC, c = rem % TC;
        int ih = reflect_i(oh0 + r - 3, H);
        int iw = reflect_i(ow0 + c - 3, W);
        s[p][r][c] = xn[(size_t)p * H * W + (size_t)ih * W + iw];
    }
    __syncthreads();

    float acc[OCPT];
#pragma unroll
    for (int j = 0; j < OCPT; ++j) acc[j] = 0.f;

    for (int ic = 0; ic < CIN; ++ic) {
        const float* wp = w + ((size_t)oc0 * CIN + ic) * 49;
#pragma unroll
        for (int kh = 0; kh < 7; ++kh) {
#pragma unroll
            for (int kw = 0; kw < 7; ++kw) {
                float vt = s[ic][ty + kh][tx + kw];
#pragma unroll
                for (int j = 0; j < OCPT; ++j)
                    acc[j] += vt * wp[(size_t)j * CIN * 49 + kh * 7 + kw];
            }
        }
    }

    int oh = oh0 + ty, ow = ow0 + tx;
    float sv[OCPT], ssv[OCPT];
#pragma unroll
    for (int j = 0; j < OCPT; ++j) {
        float r = acc[j] + b[oc0 + j];
        y[(((size_t)n * Cout + oc0 + j) * H + oh) * W + ow] = r;
        sv[j] = r;
        ssv[j] = r * r;
    }
    stats_block_store<OCPT>(sv, ssv, spart, sspart, P, blockIdx.x, n * Cout + oc0);
}

// ---------------- 7x7 conv, ic-split partial (L7) ----------------
template <int CINTOT, int ICPB, int OCPT>
__global__ __launch_bounds__(256) void conv7_part(
    const float* __restrict__ x, const float* __restrict__ w,
    float* __restrict__ part, size_t PS, int H, int W) {
    int tx = threadIdx.x & 15, ty = threadIdx.x >> 4;
    int tilesX = IDIV(W, 16);
    int ow = (blockIdx.x % tilesX) * 16 + tx;
    int oh = (blockIdx.x / tilesX) * 16 + ty;
    int ks = blockIdx.y;
    int n = blockIdx.z;
    if (ow >= W || oh >= H) return;

    int offrB[7], iwsB[7];
#pragma unroll
    for (int k = 0; k < 7; ++k) {
        offrB[k] = reflect_i(oh + k - 3, H) * W * 4;
        iwsB[k] = reflect_i(ow + k - 3, W) * 4;
    }

    float acc[OCPT];
#pragma unroll
    for (int j = 0; j < OCPT; ++j) acc[j] = 0.f;

    const char* xb = (const char*)x + (size_t)n * CINTOT * H * W * 4;
    const int ic0 = ks * ICPB;
    for (int icl = 0; icl < ICPB; ++icl) {
        int ic = ic0 + icl;
        const char* xp = xb + (size_t)ic * (H * W) * 4;  // uniform advance
        float v[49];
#pragma unroll
        for (int kh = 0; kh < 7; ++kh) {
#pragma unroll
            for (int kw = 0; kw < 7; ++kw)
                v[kh * 7 + kw] = ldb(xp, offrB[kh] + iwsB[kw]);
        }
        const float* wp = w + (size_t)ic * 49;
#pragma unroll
        for (int j = 0; j < OCPT; ++j) {
#pragma unroll
            for (int t = 0; t < 49; ++t)
                acc[j] += v[t] * wp[(size_t)j * CINTOT * 49 + t];
        }
    }
#pragma unroll
    for (int j = 0; j < OCPT; ++j)
        part[(size_t)ks * PS + (((size_t)n * OCPT + j) * H + oh) * W + ow] = acc[j];
}

// ---------------- 3x3 s2 conv: de-interleaved LDS, dbuf, fused stats --------
// Staged window per ic: 33 rows x 36 cols, split into even cols (18 used) and
// odd cols (18 used), row stride 20 -> tap reads stride-1 in tx, exact 2-way.
// Double-buffered: loads for batch k+1 issued before compute(k), ds_write
// after (T14), ONE barrier per batch. Slot offsets precomputed once.
// Requires CIN % ICB == 0. Exact-fit grid (no early return).
template <int CIN, int ICB, int OCPT>
__global__ __launch_bounds__(256) void conv3s2_dbl(
    const float* __restrict__ x, const float* __restrict__ w,
    const float* __restrict__ b, float* __restrict__ y,
    float* __restrict__ spart, float* __restrict__ sspart, int P,
    int Cout, int Hin, int Win, int Hout, int Wout) {
    constexpr int RR = 33, RS = 20;
    constexpr int TOT = ICB * RR * 9;              // float4 slots per batch
    constexpr int SLOTS = (TOT + 255) / 256;
    __shared__ float sE[2][ICB][RR][RS];
    __shared__ float sO[2][ICB][RR][RS];

    int tx = threadIdx.x & 15, ty = threadIdx.x >> 4;
    int tilesX = Wout >> 4;
    int bx = blockIdx.x % tilesX, by = blockIdx.x / tilesX;
    int oc0 = blockIdx.y * OCPT;
    int n = blockIdx.z;
    int oh = by * 16 + ty, ow = bx * 16 + tx;
    int ih0 = by * 32 - 1;
    int c0a = bx * 32 - 4;
    const int HW = Hin * Win;
    const float* xn = x + (size_t)n * CIN * HW;

    // ---- precompute stage slots (once) ----
    int goff[SLOTS], lidx[SLOTS];
    bool vld[SLOTS], okk[SLOTS];
#pragma unroll
    for (int s2 = 0; s2 < SLOTS; ++s2) {
        int q = threadIdx.x + 256 * s2;
        vld[s2] = q < TOT;
        int qq = vld[s2] ? q : 0;
        int icq = qq / (RR * 9);
        int rem = qq - icq * (RR * 9);
        int r = rem / 9, f = rem - r * 9;
        int ih = ih0 + r;
        int cb = c0a + f * 4;
        okk[s2] = vld[s2] && (ih >= 0) && (ih < Hin) && (cb >= 0);
        goff[s2] = okk[s2] ? (icq * HW + ih * Win + cb) : 0;
        lidx[s2] = (icq * RR + r) * RS + 2 * f;
    }

    float acc[OCPT];
#pragma unroll
    for (int j = 0; j < OCPT; ++j) acc[j] = 0.f;

    float4 st[SLOTS];
    auto loadregs = [&](int icb) {
        const float* xbat = xn + (size_t)icb * HW;   // uniform advance
#pragma unroll
        for (int s2 = 0; s2 < SLOTS; ++s2)
            st[s2] = okk[s2] ? *(const float4*)(xbat + goff[s2])
                             : make_float4(0.f, 0.f, 0.f, 0.f);
    };
    auto writelds = [&](int bufi) {
        float* be = &sE[bufi][0][0][0];
        float* bo = &sO[bufi][0][0][0];
#pragma unroll
        for (int s2 = 0; s2 < SLOTS; ++s2) {
            if (vld[s2]) {
                be[lidx[s2]] = st[s2].x; be[lidx[s2] + 1] = st[s2].z;
                bo[lidx[s2]] = st[s2].y; bo[lidx[s2] + 1] = st[s2].w;
            }
        }
    };

    loadregs(0);
    writelds(0);
    __syncthreads();
    int buf = 0;
    for (int ic0 = 0; ic0 < CIN; ic0 += ICB) {
        bool more = (ic0 + ICB) < CIN;
        if (more) loadregs(ic0 + ICB);   // issue next-batch loads EARLY
        // ---- compute current batch from LDS ----
#pragma unroll
        for (int icl = 0; icl < ICB; ++icl) {
            float t0[9];
#pragma unroll
            for (int kh = 0; kh < 3; ++kh) {
                int rr = 2 * ty + kh;
                t0[kh * 3 + 0] = sO[buf][icl][rr][tx + 1];
                t0[kh * 3 + 1] = sE[buf][icl][rr][tx + 2];
                t0[kh * 3 + 2] = sO[buf][icl][rr][tx + 2];
            }
            const float* wp = w + ((size_t)oc0 * CIN + ic0 + icl) * 9;
#pragma unroll
            for (int j = 0; j < OCPT; ++j) {
#pragma unroll
                for (int t = 0; t < 9; ++t)
                    acc[j] += t0[t] * wp[(size_t)j * CIN * 9 + t];
            }
        }
        if (more) writelds(buf ^ 1);     // vmcnt wait lands here, hidden
        __syncthreads();                 // single barrier per batch
        buf ^= 1;
    }

    float sv[OCPT], ssv[OCPT];
#pragma unroll
    for (int j = 0; j < OCPT; ++j) {
        float r = acc[j] + b[oc0 + j];
        y[(((size_t)n * Cout + oc0 + j) * Hout + oh) * Wout + ow] = r;
        sv[j] = r;
        ssv[j] = r * r;
    }
    stats_block_store<OCPT>(sv, ssv, spart, sspart, P, blockIdx.x, n * Cout + oc0);
}

// ---------------- 3x3 s2 transposed conv, quad, prefetch, fused stats -------
// torch weight layout w[Cin][Cout][3][3]; output quad at (2qy,2qx).
// requires CIN % (2*ICB) == 0. No early return: clamped addrs + masks so all
// threads reach the stats barrier.
template <int CIN, int ICB, int OCPT>
__global__ __launch_bounds__(256) void convt3_v4s(
    const float* __restrict__ x, const float* __restrict__ w,
    const float* __restrict__ b, float* __restrict__ y,
    float* __restrict__ spart, float* __restrict__ sspart, int P,
    int Cout, int Hin, int Win, int Hout, int Wout) {
    int tx = threadIdx.x & 15, ty = threadIdx.x >> 4;
    int tilesX = IDIV(Win, 16);
    int qx = (blockIdx.x % tilesX) * 16 + tx;
    int qy = (blockIdx.x / tilesX) * 16 + ty;
    int oc0 = blockIdx.y * OCPT;
    int n = blockIdx.z;
    bool valid = (qx < Win) && (qy < Hin);
    int qxc = min(qx, Win - 1), qyc = min(qy, Hin - 1);
    bool xin = valid && (qx + 1 < Win), yin = valid && (qy + 1 < Hin);
    int o01 = xin ? 1 : 0, o10 = yin ? Win : 0;
    float m01 = xin ? 1.f : 0.f, m10 = yin ? 1.f : 0.f, m11 = m01 * m10;

    // per-lane byte offsets of the 2x2 input quad within a plane
    int p00 = (qyc * Win + qxc) * 4;
    int p01 = p00 + o01 * 4;
    int p10 = p00 + o10 * 4;
    int p11 = p00 + (o01 + o10) * 4;

    float a00[OCPT], a01[OCPT], a10[OCPT], a11[OCPT];
#pragma unroll
    for (int j = 0; j < OCPT; ++j) { a00[j] = a01[j] = a10[j] = a11[j] = 0.f; }

    const char* xb = (const char*)x + (size_t)n * CIN * Hin * Win * 4;  // uniform
    const int HWb = Hin * Win * 4;

    float va[ICB][4], vb[ICB][4];
    auto load = [&](float (&v)[ICB][4], int ic0) {
#pragma unroll
        for (int icl = 0; icl < ICB; ++icl) {
            const char* xp = xb + (size_t)(ic0 + icl) * HWb;  // uniform advance
            v[icl][0] = ldb(xp, p00);
            v[icl][1] = ldb(xp, p01) * m01;
            v[icl][2] = ldb(xp, p10) * m10;
            v[icl][3] = ldb(xp, p11) * m11;
        }
    };
    auto fma = [&](const float (&v)[ICB][4], int ic0) {
#pragma unroll
        for (int icl = 0; icl < ICB; ++icl) {
            const float* wp = w + ((size_t)(ic0 + icl) * Cout + oc0) * 9;
#pragma unroll
            for (int j = 0; j < OCPT; ++j) {
                const float* wj = wp + j * 9;
                float w0 = wj[0], w1 = wj[1], w2 = wj[2];
                float w3 = wj[3], w4 = wj[4], w5 = wj[5];
                float w6 = wj[6], w7 = wj[7], w8 = wj[8];
                a00[j] += w4 * v[icl][0];
                a01[j] += w5 * v[icl][0] + w3 * v[icl][1];
                a10[j] += w7 * v[icl][0] + w1 * v[icl][2];
                a11[j] += w8 * v[icl][0] + w6 * v[icl][1] + w2 * v[icl][2] + w0 * v[icl][3];
            }
        }
    };

    load(va, 0);
    for (int ic0 = 0; ic0 < CIN; ic0 += 2 * ICB) {
        load(vb, ic0 + ICB);
        fma(va, ic0);
        load(va, min(ic0 + 2 * ICB, CIN - ICB));
        fma(vb, ic0 + ICB);
    }

    int oh = 2 * qy, ow = 2 * qx;
    float sv[OCPT], ssv[OCPT];
#pragma unroll
    for (int j = 0; j < OCPT; ++j) {
        float s = 0.f, ss = 0.f;
        if (valid) {
            float bb = b[oc0 + j];
            float* yp = y + (((size_t)n * Cout + oc0 + j) * Hout + oh) * Wout + ow;
            float t00 = a00[j] + bb;
            yp[0] = t00; s += t00; ss += t00 * t00;
            if (xin) { float t = a01[j] + bb; yp[1] = t; s += t; ss += t * t; }
            if (yin) { float t = a10[j] + bb; yp[Wout] = t; s += t; ss += t * t; }
            if (xin && yin) { float t = a11[j] + bb; yp[Wout + 1] = t; s += t; ss += t * t; }
        }
        sv[j] = s; ssv[j] = ss;
    }
    stats_block_store<OCPT>(sv, ssv, spart, sspart, P, blockIdx.x, n * Cout + oc0);
}

// ---------------- inorm apply, float4 coalesced (plane % 4 == 0) ------------
__global__ void inorm_apply4(float* __restrict__ x, const float* __restrict__ mean,
                             const float* __restrict__ inv, int plane4) {
    int pc = blockIdx.y;
    int i = blockIdx.x * 256 + threadIdx.x;
    if (i >= plane4) return;
    float m = mean[pc], iv = inv[pc];
    float4* p = (float4*)(x + (size_t)pc * plane4 * 4);
    float4 v = p[i];
    v.x = fmaxf(0.f, (v.x - m) * iv);
    v.y = fmaxf(0.f, (v.y - m) * iv);
    v.z = fmaxf(0.f, (v.z - m) * iv);
    v.w = fmaxf(0.f, (v.w - m) * iv);
    p[i] = v;
}

// ---------------- inorm apply, 1 elem/thread coalesced (any plane) ----------
__global__ void inorm_apply1(float* __restrict__ x, const float* __restrict__ mean,
                             const float* __restrict__ inv, int plane) {
    int pc = blockIdx.y;
    int i = blockIdx.x * 256 + threadIdx.x;
    if (i >= plane) return;
    float m = mean[pc], iv = inv[pc];
    size_t idx = (size_t)pc * plane + i;
    x[idx] = fmaxf(0.f, (x[idx] - m) * iv);
}

// ---------------- segment mean (accum fused with L7 finalize) ---------------
__global__ void seg_zero(float* __restrict__ bins) {
    if (threadIdx.x < 128) bins[threadIdx.x] = 0.f;
}

// reads the 4 ic-split partials + bias, computes tanh inline; a7 never built.
__global__ void seg_accum_f(const float* __restrict__ part, const float* __restrict__ b,
                            const int* __restrict__ inst, float* __restrict__ bins,
                            int HW, size_t PS) {
    __shared__ float ls[128];  // 96 sums + 32 counts
    for (int i = threadIdx.x; i < 128; i += 256) ls[i] = 0.f;
    __syncthreads();
    int n = blockIdx.y;
    int i = blockIdx.x * 256 + threadIdx.x;
    if (i < HW) {
        int id = inst[(size_t)n * HW + i];
#pragma unroll
        for (int c = 0; c < 3; ++c) {
            size_t off = ((size_t)(n * 3 + c)) * HW + i;
            float v = part[off] + part[PS + off] + part[2 * PS + off] +
                      part[3 * PS + off] + b[c];
            atomicAdd(&ls[id * 3 + c], tanhf(v));
        }
        atomicAdd(&ls[96 + id], 1.0f);
    }
    __syncthreads();
    for (int i2 = threadIdx.x; i2 < 128; i2 += 256)
        if (ls[i2] != 0.f) atomicAdd(&bins[i2], ls[i2]);
}

__global__ void seg_scatter(const float* __restrict__ bins, const int* __restrict__ inst,
                            float* __restrict__ out, int HW) {
    int n = blockIdx.y;
    int i = blockIdx.x * 256 + threadIdx.x;
    if (i >= HW) return;
    int id = inst[(size_t)n * HW + i];
    float c = fmaxf(bins[96 + id], 1.0f);
    out[((size_t)n * 3 + 0) * HW + i] = bins[id * 3 + 0] / c;
    out[((size_t)n * 3 + 1) * HW + i] = bins[id * 3 + 1] / c;
    out[((size_t)n * 3 + 2) * HW + i] = bins[id * 3 + 2] / c;
}

// ---------------------------------------------------------------------------
extern "C" void kernel_launch(void* const* d_in, const int* in_sizes, int n_in,
                              void* d_out, int out_size, void* d_ws, size_t ws_size,
                              hipStream_t stream) {
    const float* x = (const float*)d_in[0];
    const int* inst = (const int*)d_in[1];
    const float* W[8];
    const float* B[8];
    for (int i = 0; i < 8; ++i) {
        W[i] = (const float*)d_in[2 + 2 * i];
        B[i] = (const float*)d_in[3 + 2 * i];
    }
    float* ws = (float*)d_ws;

    // End-aligned ping-pong arena (R2/R6 proven)
    const size_t S = 25165824;  // floats
    float* a0 = ws;                  // [8,32,256,256]
    float* a1 = ws + 16777216;       // [8,64,128,128]
    float* a2 = ws;                  // [8,128,64,64]
    float* a3 = ws + 23068672;       // [8,256,32,32]
    float* a4 = ws;                  // [8,128,63,63]
    float* a5 = ws + 17165824;       // [8,64,125,125]
    float* a6 = ws;                  // [8,32,249,249]  0 .. 15.87M
    float* PART = ws + 16000000;     // 4 x 1488024 floats (gap above a6)
    float* mean = ws + S;            // 2048
    float* inv = mean + 2048;        // 2048
    float* bins = inv + 2048;        // 128
    float* spart = bins + 128;       // 65536 (max nT*P = 256*256)
    float* sspart = spart + 65536;   // 65536

    // L0: 7x7 reflect, 3->32, 256. LDS-staged, OCPT=8, 8192 blocks
    conv7_lds<3, 8><<<dim3(256, 4, 8), 256, 0, stream>>>(
        x, W[0], B[0], a0, spart, sspart, 256, 32, 256, 256);
    stat_reduce_mi<<<dim3(256), 64, 0, stream>>>(spart, sspart, mean, inv, 256, 256, 1.f / 65536.f);
    inorm_apply4<<<dim3(IDIV(16384, 256), 256), 256, 0, stream>>>(a0, mean, inv, 16384);

    // L1: 3x3 s2, 32->64, 256->128. de-interleaved dbuf LDS, 4096 blocks
    conv3s2_dbl<32, 2, 8><<<dim3(64, 8, 8), 256, 0, stream>>>(
        a0, W[1], B[1], a1, spart, sspart, 512, 64, 256, 256, 128, 128);
    stat_reduce_mi<<<dim3(512), 64, 0, stream>>>(spart, sspart, mean, inv, 512, 64, 1.f / 16384.f);
    inorm_apply4<<<dim3(IDIV(4096, 256), 512), 256, 0, stream>>>(a1, mean, inv, 4096);

    // L2: 3x3 s2, 64->128, 128->64. 2048 blocks
    conv3s2_dbl<64, 2, 8><<<dim3(16, 16, 8), 256, 0, stream>>>(
        a1, W[2], B[2], a2, spart, sspart, 1024, 128, 128, 128, 64, 64);
    stat_reduce_mi<<<dim3(1024), 64, 0, stream>>>(spart, sspart, mean, inv, 1024, 16, 1.f / 4096.f);
    inorm_apply4<<<dim3(IDIV(1024, 256), 1024), 256, 0, stream>>>(a2, mean, inv, 1024);

    // L3: 3x3 s2, 128->256, 64->32. 1024 blocks
    conv3s2_dbl<128, 2, 8><<<dim3(4, 32, 8), 256, 0, stream>>>(
        a2, W[3], B[3], a3, spart, sspart, 2048, 256, 64, 64, 32, 32);
    stat_reduce_mi<<<dim3(2048), 64, 0, stream>>>(spart, sspart, mean, inv, 2048, 4, 1.f / 1024.f);
    inorm_apply4<<<dim3(1, 2048), 256, 0, stream>>>(a3, mean, inv, 256);

    // L4: convT, 256->128, 32->63. R19 config (OCPT=4)
    convt3_v4s<256, 4, 4><<<dim3(4, 32, 8), 256, 0, stream>>>(
        a3, W[4], B[4], a4, spart, sspart, 1024, 128, 32, 32, 63, 63);
    stat_reduce_mi<<<dim3(1024), 64, 0, stream>>>(spart, sspart, mean, inv, 1024, 4, 1.f / 3969.f);
    inorm_apply1<<<dim3(IDIV(3969, 256), 1024), 256, 0, stream>>>(a4, mean, inv, 3969);

    // L5: convT, 128->64, 63->125. R19 config (OCPT=4, 2048 blocks)
    convt3_v4s<128, 4, 4><<<dim3(16, 16, 8), 256, 0, stream>>>(
        a4, W[5], B[5], a5, spart, sspart, 512, 64, 63, 63, 125, 125);
    stat_reduce_mi<<<dim3(512), 64, 0, stream>>>(spart, sspart, mean, inv, 512, 16, 1.f / 15625.f);
    inorm_apply1<<<dim3(IDIV(15625, 256), 512), 256, 0, stream>>>(a5, mean, inv, 15625);

    // L6: convT, 64->32, 125->249. R19 config (OCPT=4, 4096 blocks)
    convt3_v4s<64, 4, 4><<<dim3(64, 8, 8), 256, 0, stream>>>(
        a5, W[6], B[6], a6, spart, sspart, 256, 32, 125, 125, 249, 249);
    stat_reduce_mi<<<dim3(256), 64, 0, stream>>>(spart, sspart, mean, inv, 256, 64, 1.f / 62001.f);
    inorm_apply1<<<dim3(IDIV(62001, 256), 256), 256, 0, stream>>>(a6, mean, inv, 62001);

    // L7: 7x7 reflect, 32->3, 249 — ic-split x4; finalize fused into seg_accum
    conv7_part<32, 8, 3><<<dim3(256, 4, 8), 256, 0, stream>>>(a6, W[7], PART, 1488024, 249, 249);

    // segment mean (accum reads partials + bias + tanh inline)
    seg_zero<<<1, 128, 0, stream>>>(bins);
    seg_accum_f<<<dim3(IDIV(62001, 256), 8), 256, 0, stream>>>(
        PART, B[7], inst, bins, 62001, 1488024);
    seg_scatter<<<dim3(IDIV(62001, 256), 8), 256, 0, stream>>>(bins, inst, (float*)d_out, 62001);
}

// Round 7
// 1331.425 us; speedup vs baseline: 1.1859x; 1.1859x over previous
//
#include <hip/hip_runtime.h>
#include <math.h>

// ---------------------------------------------------------------------------
// FeatureEncoder R25 = R19 skeleton + conv7 LDS staging on L0 AND L7 only.
// R23/R24 verdict: LDS staging for stride-2 conv3s2 is a dead axis (write
// scatter = even-bank 4-way conflicts 14.3M; even perfect version's LDS-pipe
// cost ~44us/layer vs 31us FMA floor). But 7x7 convs are the right target:
// 49 unit-stride taps/px, reflect resolved once at stage, 6.5-17KB LDS.
// R24 evidence: conv7_lds dropped L0 out of the top-5 profile.
// - L0: conv7_lds (R24-proven, CIN=3 staged, RS=24 2-way-free)
// - L7: conv7_part_lds (same structure, 8 planes/dispatch, store-guarded
//   boundary, no early return - barrier safe)
// - L1-L3: EXACT R19 conv3s2_v3s (182us verified)
// - convT / inorm / stats / seg / arena: exact R19.
// ---------------------------------------------------------------------------

#define IDIV(a, b) (((a) + (b) - 1) / (b))

__device__ __forceinline__ int reflect_i(int i, int n) {
    i = i < 0 ? -i : i;
    return i >= n ? 2 * n - 2 - i : i;
}

__device__ __forceinline__ float ldb(const char* base, int boff) {
    return *(const float*)(base + boff);
}

// block-level (sum,sumsq) reduction for OCPT channels -> partial store
template <int OCPT>
__device__ __forceinline__ void stats_block_store(
    const float* sv, const float* ssv, float* __restrict__ spart,
    float* __restrict__ sspart, int P, int tile, int pc0) {
    __shared__ float redS[OCPT], redSS[OCPT];
    if (threadIdx.x < OCPT) { redS[threadIdx.x] = 0.f; redSS[threadIdx.x] = 0.f; }
    __syncthreads();
    int lane = threadIdx.x & 63;
#pragma unroll
    for (int j = 0; j < OCPT; ++j) {
        float s = sv[j], ss = ssv[j];
#pragma unroll
        for (int o = 32; o > 0; o >>= 1) {
            s += __shfl_down(s, o);
            ss += __shfl_down(ss, o);
        }
        if (lane == 0) { atomicAdd(&redS[j], s); atomicAdd(&redSS[j], ss); }  // LDS atomics
    }
    __syncthreads();
    if (threadIdx.x < OCPT) {
        spart[(size_t)tile * P + pc0 + threadIdx.x] = redS[threadIdx.x];
        sspart[(size_t)tile * P + pc0 + threadIdx.x] = redSS[threadIdx.x];
    }
}

// fold [nT][P] partials -> mean, inv (one wavefront per plane)
__global__ __launch_bounds__(64) void stat_reduce_mi(
    const float* __restrict__ sp, const float* __restrict__ ssp,
    float* __restrict__ mean, float* __restrict__ inv, int P, int nT,
    float rcp_plane) {
    int p = blockIdx.x;
    float a = 0.f, bsum = 0.f;
    for (int t = threadIdx.x; t < nT; t += 64) {
        a += sp[(size_t)t * P + p];
        bsum += ssp[(size_t)t * P + p];
    }
#pragma unroll
    for (int o = 32; o > 0; o >>= 1) {
        a += __shfl_down(a, o);
        bsum += __shfl_down(bsum, o);
    }
    if (threadIdx.x == 0) {
        float m = a * rcp_plane;
        float var = bsum * rcp_plane - m * m;
        mean[p] = m;
        inv[p] = rsqrtf(var + 1e-5f);
    }
}

// ---------------- 7x7 same-conv (L0), LDS-staged tile, fused stats ----------
// 16x16 outputs/block; staged window 22x22 per plane (reflect applied at
// stage). Row stride 24 -> tap reads exactly 2-way bank (free). Exact-fit.
template <int CIN, int OCPT>
__global__ __launch_bounds__(256) void conv7_lds(
    const float* __restrict__ x, const float* __restrict__ w,
    const float* __restrict__ b, float* __restrict__ y,
    float* __restrict__ spart, float* __restrict__ sspart, int P,
    int Cout, int H, int W) {
    constexpr int TR = 22, TC = 22, RS = 24;
    __shared__ float s[CIN][TR][RS];
    int tx = threadIdx.x & 15, ty = threadIdx.x >> 4;
    int tilesX = W / 16;
    int bx = blockIdx.x % tilesX, by = blockIdx.x / tilesX;
    int oh0 = by * 16, ow0 = bx * 16;
    int oc0 = blockIdx.y * OCPT;
    int n = blockIdx.z;
    const float* xn = x + (size_t)n * CIN * H * W;

    for (int q = threadIdx.x; q < CIN * TR * TC; q += 256) {
        int p = q / (TR * TC), rem = q % (TR * TC);
        int r = rem / TC, c = rem % TC;
        int ih = reflect_i(oh0 + r - 3, H);
        int iw = reflect_i(ow0 + c - 3, W);
        s[p][r][c] = xn[(size_t)p * H * W + (size_t)ih * W + iw];
    }
    __syncthreads();

    float acc[OCPT];
#pragma unroll
    for (int j = 0; j < OCPT; ++j) acc[j] = 0.f;

    for (int ic = 0; ic < CIN; ++ic) {
        const float* wp = w + ((size_t)oc0 * CIN + ic) * 49;
#pragma unroll
        for (int kh = 0; kh < 7; ++kh) {
#pragma unroll
            for (int kw = 0; kw < 7; ++kw) {
                float vt = s[ic][ty + kh][tx + kw];
#pragma unroll
                for (int j = 0; j < OCPT; ++j)
                    acc[j] += vt * wp[(size_t)j * CIN * 49 + kh * 7 + kw];
            }
        }
    }

    int oh = oh0 + ty, ow = ow0 + tx;
    float sv[OCPT], ssv[OCPT];
#pragma unroll
    for (int j = 0; j < OCPT; ++j) {
        float r = acc[j] + b[oc0 + j];
        y[(((size_t)n * Cout + oc0 + j) * H + oh) * W + ow] = r;
        sv[j] = r;
        ssv[j] = r * r;
    }
    stats_block_store<OCPT>(sv, ssv, spart, sspart, P, blockIdx.x, n * Cout + oc0);
}

// ---------------- 7x7 conv, ic-split partial (L7), LDS-staged ---------------
// Same staging structure as conv7_lds, 8 planes/dispatch. Non-exact grid
// (249 = 16*16-7): NO early return (stage barrier needs all threads);
// stage coords reflect-clamped, final store guarded.
template <int CINTOT, int ICPB, int OCPT>
__global__ __launch_bounds__(256) void conv7_part_lds(
    const float* __restrict__ x, const float* __restrict__ w,
    float* __restrict__ part, size_t PS, int H, int W) {
    constexpr int TR = 22, TC = 22, RS = 24;
    __shared__ float s[ICPB][TR][RS];
    int tx = threadIdx.x & 15, ty = threadIdx.x >> 4;
    int tilesX = IDIV(W, 16);
    int bx = blockIdx.x % tilesX, by = blockIdx.x / tilesX;
    int oh0 = by * 16, ow0 = bx * 16;
    int ks = blockIdx.y;
    int n = blockIdx.z;
    const int ic0 = ks * ICPB;
    const float* xn = x + (size_t)n * CINTOT * H * W;

    for (int q = threadIdx.x; q < ICPB * TR * TC; q += 256) {
        int p = q / (TR * TC), rem = q % (TR * TC);
        int r = rem / TC, c = rem % TC;
        // oh0+r-3 max = 240+21-3 = 258 <= 2*249-3, reflect_i safe
        int ih = reflect_i(oh0 + r - 3, H);
        int iw = reflect_i(ow0 + c - 3, W);
        s[p][r][c] = xn[(size_t)(ic0 + p) * H * W + (size_t)ih * W + iw];
    }
    __syncthreads();

    float acc[OCPT];
#pragma unroll
    for (int j = 0; j < OCPT; ++j) acc[j] = 0.f;

#pragma unroll
    for (int icl = 0; icl < ICPB; ++icl) {
        const float* wp = w + (size_t)(ic0 + icl) * 49;
#pragma unroll
        for (int kh = 0; kh < 7; ++kh) {
#pragma unroll
            for (int kw = 0; kw < 7; ++kw) {
                float vt = s[icl][ty + kh][tx + kw];
#pragma unroll
                for (int j = 0; j < OCPT; ++j)
                    acc[j] += vt * wp[(size_t)j * CINTOT * 49 + kh * 7 + kw];
            }
        }
    }

    int oh = oh0 + ty, ow = ow0 + tx;
    if (oh < H && ow < W) {
#pragma unroll
        for (int j = 0; j < OCPT; ++j)
            part[(size_t)ks * PS + (((size_t)n * OCPT + j) * H + oh) * W + ow] = acc[j];
    }
}

// ---------------- 3x3 s2 conv, branchless batched loads, fused stats (R19) --
template <int CIN, int ICB, int OCPT>
__global__ __launch_bounds__(256) void conv3s2_v3s(
    const float* __restrict__ x, const float* __restrict__ w,
    const float* __restrict__ b, float* __restrict__ y,
    float* __restrict__ spart, float* __restrict__ sspart, int P,
    int Cout, int Hin, int Win, int Hout, int Wout) {
    int tx = threadIdx.x & 15, ty = threadIdx.x >> 4;
    int tilesX = Wout >> 4;
    int ow = (blockIdx.x % tilesX) * 16 + tx;
    int oh = (blockIdx.x / tilesX) * 16 + ty;
    int oc0 = blockIdx.y * OCPT;
    int n = blockIdx.z;

    int ih0 = oh * 2 - 1, iw0 = ow * 2 - 1;
    int boff[9];   // per-lane byte offsets within a plane
    float mm[9];
#pragma unroll
    for (int kh = 0; kh < 3; ++kh) {
        int ih = ih0 + kh;
        int ihc = min(max(ih, 0), Hin - 1);
        float mr = (ih >= 0 && ih < Hin) ? 1.f : 0.f;
#pragma unroll
        for (int kw = 0; kw < 3; ++kw) {
            int iw = iw0 + kw;
            int iwc = min(max(iw, 0), Win - 1);
            float mc = (iw >= 0 && iw < Win) ? 1.f : 0.f;
            boff[kh * 3 + kw] = (ihc * Win + iwc) * 4;
            mm[kh * 3 + kw] = mr * mc;
        }
    }

    float acc[OCPT];
#pragma unroll
    for (int j = 0; j < OCPT; ++j) acc[j] = 0.f;

    const char* xb = (const char*)x + (size_t)n * CIN * Hin * Win * 4;
    for (int ic0 = 0; ic0 < CIN; ic0 += ICB) {
        float v[ICB][9];
#pragma unroll
        for (int icl = 0; icl < ICB; ++icl) {
            const char* xp = xb + (size_t)(ic0 + icl) * (Hin * Win) * 4;  // uniform
#pragma unroll
            for (int t = 0; t < 9; ++t) v[icl][t] = ldb(xp, boff[t]) * mm[t];
        }
#pragma unroll
        for (int icl = 0; icl < ICB; ++icl) {
            const float* wp = w + ((size_t)oc0 * CIN + ic0 + icl) * 9;
#pragma unroll
            for (int j = 0; j < OCPT; ++j) {
#pragma unroll
                for (int t = 0; t < 9; ++t)
                    acc[j] += v[icl][t] * wp[(size_t)j * CIN * 9 + t];
            }
        }
    }
    float sv[OCPT], ssv[OCPT];
#pragma unroll
    for (int j = 0; j < OCPT; ++j) {
        float r = acc[j] + b[oc0 + j];
        y[(((size_t)n * Cout + oc0 + j) * Hout + oh) * Wout + ow] = r;
        sv[j] = r;
        ssv[j] = r * r;
    }
    stats_block_store<OCPT>(sv, ssv, spart, sspart, P, blockIdx.x, n * Cout + oc0);
}

// ---------------- 3x3 s2 transposed conv, quad, prefetch, fused stats -------
// torch weight layout w[Cin][Cout][3][3]; output quad at (2qy,2qx).
// requires CIN % (2*ICB) == 0. No early return: clamped addrs + masks so all
// threads reach the stats barrier.
template <int CIN, int ICB, int OCPT>
__global__ __launch_bounds__(256) void convt3_v4s(
    const float* __restrict__ x, const float* __restrict__ w,
    const float* __restrict__ b, float* __restrict__ y,
    float* __restrict__ spart, float* __restrict__ sspart, int P,
    int Cout, int Hin, int Win, int Hout, int Wout) {
    int tx = threadIdx.x & 15, ty = threadIdx.x >> 4;
    int tilesX = IDIV(Win, 16);
    int qx = (blockIdx.x % tilesX) * 16 + tx;
    int qy = (blockIdx.x / tilesX) * 16 + ty;
    int oc0 = blockIdx.y * OCPT;
    int n = blockIdx.z;
    bool valid = (qx < Win) && (qy < Hin);
    int qxc = min(qx, Win - 1), qyc = min(qy, Hin - 1);
    bool xin = valid && (qx + 1 < Win), yin = valid && (qy + 1 < Hin);
    int o01 = xin ? 1 : 0, o10 = yin ? Win : 0;
    float m01 = xin ? 1.f : 0.f, m10 = yin ? 1.f : 0.f, m11 = m01 * m10;

    // per-lane byte offsets of the 2x2 input quad within a plane
    int p00 = (qyc * Win + qxc) * 4;
    int p01 = p00 + o01 * 4;
    int p10 = p00 + o10 * 4;
    int p11 = p00 + (o01 + o10) * 4;

    float a00[OCPT], a01[OCPT], a10[OCPT], a11[OCPT];
#pragma unroll
    for (int j = 0; j < OCPT; ++j) { a00[j] = a01[j] = a10[j] = a11[j] = 0.f; }

    const char* xb = (const char*)x + (size_t)n * CIN * Hin * Win * 4;  // uniform
    const int HWb = Hin * Win * 4;

    float va[ICB][4], vb[ICB][4];
    auto load = [&](float (&v)[ICB][4], int ic0) {
#pragma unroll
        for (int icl = 0; icl < ICB; ++icl) {
            const char* xp = xb + (size_t)(ic0 + icl) * HWb;  // uniform advance
            v[icl][0] = ldb(xp, p00);
            v[icl][1] = ldb(xp, p01) * m01;
            v[icl][2] = ldb(xp, p10) * m10;
            v[icl][3] = ldb(xp, p11) * m11;
        }
    };
    auto fma = [&](const float (&v)[ICB][4], int ic0) {
#pragma unroll
        for (int icl = 0; icl < ICB; ++icl) {
            const float* wp = w + ((size_t)(ic0 + icl) * Cout + oc0) * 9;
#pragma unroll
            for (int j = 0; j < OCPT; ++j) {
                const float* wj = wp + j * 9;
                float w0 = wj[0], w1 = wj[1], w2 = wj[2];
                float w3 = wj[3], w4 = wj[4], w5 = wj[5];
                float w6 = wj[6], w7 = wj[7], w8 = wj[8];
                a00[j] += w4 * v[icl][0];
                a01[j] += w5 * v[icl][0] + w3 * v[icl][1];
                a10[j] += w7 * v[icl][0] + w1 * v[icl][2];
                a11[j] += w8 * v[icl][0] + w6 * v[icl][1] + w2 * v[icl][2] + w0 * v[icl][3];
            }
        }
    };

    load(va, 0);
    for (int ic0 = 0; ic0 < CIN; ic0 += 2 * ICB) {
        load(vb, ic0 + ICB);
        fma(va, ic0);
        load(va, min(ic0 + 2 * ICB, CIN - ICB));
        fma(vb, ic0 + ICB);
    }

    int oh = 2 * qy, ow = 2 * qx;
    float sv[OCPT], ssv[OCPT];
#pragma unroll
    for (int j = 0; j < OCPT; ++j) {
        float s = 0.f, ss = 0.f;
        if (valid) {
            float bb = b[oc0 + j];
            float* yp = y + (((size_t)n * Cout + oc0 + j) * Hout + oh) * Wout + ow;
            float t00 = a00[j] + bb;
            yp[0] = t00; s += t00; ss += t00 * t00;
            if (xin) { float t = a01[j] + bb; yp[1] = t; s += t; ss += t * t; }
            if (yin) { float t = a10[j] + bb; yp[Wout] = t; s += t; ss += t * t; }
            if (xin && yin) { float t = a11[j] + bb; yp[Wout + 1] = t; s += t; ss += t * t; }
        }
        sv[j] = s; ssv[j] = ss;
    }
    stats_block_store<OCPT>(sv, ssv, spart, sspart, P, blockIdx.x, n * Cout + oc0);
}

// ---------------- inorm apply, float4 coalesced (plane % 4 == 0) ------------
__global__ void inorm_apply4(float* __restrict__ x, const float* __restrict__ mean,
                             const float* __restrict__ inv, int plane4) {
    int pc = blockIdx.y;
    int i = blockIdx.x * 256 + threadIdx.x;
    if (i >= plane4) return;
    float m = mean[pc], iv = inv[pc];
    float4* p = (float4*)(x + (size_t)pc * plane4 * 4);
    float4 v = p[i];
    v.x = fmaxf(0.f, (v.x - m) * iv);
    v.y = fmaxf(0.f, (v.y - m) * iv);
    v.z = fmaxf(0.f, (v.z - m) * iv);
    v.w = fmaxf(0.f, (v.w - m) * iv);
    p[i] = v;
}

// ---------------- inorm apply, 1 elem/thread coalesced (any plane) ----------
__global__ void inorm_apply1(float* __restrict__ x, const float* __restrict__ mean,
                             const float* __restrict__ inv, int plane) {
    int pc = blockIdx.y;
    int i = blockIdx.x * 256 + threadIdx.x;
    if (i >= plane) return;
    float m = mean[pc], iv = inv[pc];
    size_t idx = (size_t)pc * plane + i;
    x[idx] = fmaxf(0.f, (x[idx] - m) * iv);
}

// ---------------- segment mean (accum fused with L7 finalize) ---------------
__global__ void seg_zero(float* __restrict__ bins) {
    if (threadIdx.x < 128) bins[threadIdx.x] = 0.f;
}

// reads the 4 ic-split partials + bias, computes tanh inline; a7 never built.
__global__ void seg_accum_f(const float* __restrict__ part, const float* __restrict__ b,
                            const int* __restrict__ inst, float* __restrict__ bins,
                            int HW, size_t PS) {
    __shared__ float ls[128];  // 96 sums + 32 counts
    for (int i = threadIdx.x; i < 128; i += 256) ls[i] = 0.f;
    __syncthreads();
    int n = blockIdx.y;
    int i = blockIdx.x * 256 + threadIdx.x;
    if (i < HW) {
        int id = inst[(size_t)n * HW + i];
#pragma unroll
        for (int c = 0; c < 3; ++c) {
            size_t off = ((size_t)(n * 3 + c)) * HW + i;
            float v = part[off] + part[PS + off] + part[2 * PS + off] +
                      part[3 * PS + off] + b[c];
            atomicAdd(&ls[id * 3 + c], tanhf(v));
        }
        atomicAdd(&ls[96 + id], 1.0f);
    }
    __syncthreads();
    for (int i2 = threadIdx.x; i2 < 128; i2 += 256)
        if (ls[i2] != 0.f) atomicAdd(&bins[i2], ls[i2]);
}

__global__ void seg_scatter(const float* __restrict__ bins, const int* __restrict__ inst,
                            float* __restrict__ out, int HW) {
    int n = blockIdx.y;
    int i = blockIdx.x * 256 + threadIdx.x;
    if (i >= HW) return;
    int id = inst[(size_t)n * HW + i];
    float c = fmaxf(bins[96 + id], 1.0f);
    out[((size_t)n * 3 + 0) * HW + i] = bins[id * 3 + 0] / c;
    out[((size_t)n * 3 + 1) * HW + i] = bins[id * 3 + 1] / c;
    out[((size_t)n * 3 + 2) * HW + i] = bins[id * 3 + 2] / c;
}

// ---------------------------------------------------------------------------
extern "C" void kernel_launch(void* const* d_in, const int* in_sizes, int n_in,
                              void* d_out, int out_size, void* d_ws, size_t ws_size,
                              hipStream_t stream) {
    const float* x = (const float*)d_in[0];
    const int* inst = (const int*)d_in[1];
    const float* W[8];
    const float* B[8];
    for (int i = 0; i < 8; ++i) {
        W[i] = (const float*)d_in[2 + 2 * i];
        B[i] = (const float*)d_in[3 + 2 * i];
    }
    float* ws = (float*)d_ws;

    // End-aligned ping-pong arena (R2/R6 proven)
    const size_t S = 25165824;  // floats
    float* a0 = ws;                  // [8,32,256,256]
    float* a1 = ws + 16777216;       // [8,64,128,128]
    float* a2 = ws;                  // [8,128,64,64]
    float* a3 = ws + 23068672;       // [8,256,32,32]
    float* a4 = ws;                  // [8,128,63,63]
    float* a5 = ws + 17165824;       // [8,64,125,125]
    float* a6 = ws;                  // [8,32,249,249]  0 .. 15.87M
    float* PART = ws + 16000000;     // 4 x 1488024 floats (gap above a6)
    float* mean = ws + S;            // 2048
    float* inv = mean + 2048;        // 2048
    float* bins = inv + 2048;        // 128
    float* spart = bins + 128;       // 65536 (max nT*P = 256*256)
    float* sspart = spart + 65536;   // 65536

    // L0: 7x7 reflect, 3->32, 256. LDS-staged, OCPT=8, 8192 blocks
    conv7_lds<3, 8><<<dim3(256, 4, 8), 256, 0, stream>>>(
        x, W[0], B[0], a0, spart, sspart, 256, 32, 256, 256);
    stat_reduce_mi<<<dim3(256), 64, 0, stream>>>(spart, sspart, mean, inv, 256, 256, 1.f / 65536.f);
    inorm_apply4<<<dim3(IDIV(16384, 256), 256), 256, 0, stream>>>(a0, mean, inv, 16384);

    // L1: 3x3 s2, 32->64, 256->128. R19 config (OCPT=8, 4096 blocks)
    conv3s2_v3s<32, 4, 8><<<dim3(64, 8, 8), 256, 0, stream>>>(
        a0, W[1], B[1], a1, spart, sspart, 512, 64, 256, 256, 128, 128);
    stat_reduce_mi<<<dim3(512), 64, 0, stream>>>(spart, sspart, mean, inv, 512, 64, 1.f / 16384.f);
    inorm_apply4<<<dim3(IDIV(4096, 256), 512), 256, 0, stream>>>(a1, mean, inv, 4096);

    // L2: 3x3 s2, 64->128, 128->64. R19 config (OCPT=8, 2048 blocks)
    conv3s2_v3s<64, 4, 8><<<dim3(16, 16, 8), 256, 0, stream>>>(
        a1, W[2], B[2], a2, spart, sspart, 1024, 128, 128, 128, 64, 64);
    stat_reduce_mi<<<dim3(1024), 64, 0, stream>>>(spart, sspart, mean, inv, 1024, 16, 1.f / 4096.f);
    inorm_apply4<<<dim3(IDIV(1024, 256), 1024), 256, 0, stream>>>(a2, mean, inv, 1024);

    // L3: 3x3 s2, 128->256, 64->32. R19 config (OCPT=8, 1024 blocks)
    conv3s2_v3s<128, 4, 8><<<dim3(4, 32, 8), 256, 0, stream>>>(
        a2, W[3], B[3], a3, spart, sspart, 2048, 256, 64, 64, 32, 32);
    stat_reduce_mi<<<dim3(2048), 64, 0, stream>>>(spart, sspart, mean, inv, 2048, 4, 1.f / 1024.f);
    inorm_apply4<<<dim3(1, 2048), 256, 0, stream>>>(a3, mean, inv, 256);

    // L4: convT, 256->128, 32->63. R19 config (OCPT=4)
    convt3_v4s<256, 4, 4><<<dim3(4, 32, 8), 256, 0, stream>>>(
        a3, W[4], B[4], a4, spart, sspart, 1024, 128, 32, 32, 63, 63);
    stat_reduce_mi<<<dim3(1024), 64, 0, stream>>>(spart, sspart, mean, inv, 1024, 4, 1.f / 3969.f);
    inorm_apply1<<<dim3(IDIV(3969, 256), 1024), 256, 0, stream>>>(a4, mean, inv, 3969);

    // L5: convT, 128->64, 63->125. R19 config (OCPT=4, 2048 blocks)
    convt3_v4s<128, 4, 4><<<dim3(16, 16, 8), 256, 0, stream>>>(
        a4, W[5], B[5], a5, spart, sspart, 512, 64, 63, 63, 125, 125);
    stat_reduce_mi<<<dim3(512), 64, 0, stream>>>(spart, sspart, mean, inv, 512, 16, 1.f / 15625.f);
    inorm_apply1<<<dim3(IDIV(15625, 256), 512), 256, 0, stream>>>(a5, mean, inv, 15625);

    // L6: convT, 64->32, 125->249. R19 config (OCPT=4, 4096 blocks)
    convt3_v4s<64, 4, 4><<<dim3(64, 8, 8), 256, 0, stream>>>(
        a5, W[6], B[6], a6, spart, sspart, 256, 32, 125, 125, 249, 249);
    stat_reduce_mi<<<dim3(256), 64, 0, stream>>>(spart, sspart, mean, inv, 256, 64, 1.f / 62001.f);
    inorm_apply1<<<dim3(IDIV(62001, 256), 256), 256, 0, stream>>>(a6, mean, inv, 62001);

    // L7: 7x7 reflect, 32->3, 249 — ic-split x4, LDS-staged
    conv7_part_lds<32, 8, 3><<<dim3(256, 4, 8), 256, 0, stream>>>(
        a6, W[7], PART, 1488024, 249, 249);

    // segment mean (accum reads partials + bias + tanh inline)
    seg_zero<<<1, 128, 0, stream>>>(bins);
    seg_accum_f<<<dim3(IDIV(62001, 256), 8), 256, 0, stream>>>(
        PART, B[7], inst, bins, 62001, 1488024);
    seg_scatter<<<dim3(IDIV(62001, 256), 8), 256, 0, stream>>>(bins, inst, (float*)d_out, 62001);
}

// Round 8
// 1265.413 us; speedup vs baseline: 1.2478x; 1.0522x over previous
//
#include <hip/hip_runtime.h>
#include <math.h>

// ---------------------------------------------------------------------------
// FeatureEncoder R26 = R25 (best, 1331us) + vectorized row loads in the
// remaining VMEM-heavy kernels:
// - conv3s2 (L1-L3): each output needs 3 CONSECUTIVE floats per kernel row
//   -> one float4 (dword-aligned dwordx4) replaces 3 scalar taps. 288 scalar
//   loads/thread -> 96 dwordx4; TCP line-service ~92us/layer -> ~37us model.
//   Left edge (iw0=-1, ow==0 lanes only) via clamped base + cndmask shift;
//   right-edge over-read (1 elem) lands in adjacent allocated arena, unused.
//   ICB 4->2 to cap float4 register footprint (~60 VGPR; R22 lesson).
// - convT (L4-L6): taps (p00,p01) and (p10,p11) are adjacent -> two float2
//   loads replace 4 scalar loads.
// L0/L7 7x7 LDS staging (R25-proven, ~100us win) and everything else intact.
// ---------------------------------------------------------------------------

#define IDIV(a, b) (((a) + (b) - 1) / (b))

__device__ __forceinline__ int reflect_i(int i, int n) {
    i = i < 0 ? -i : i;
    return i >= n ? 2 * n - 2 - i : i;
}

__device__ __forceinline__ float ldb(const char* base, int boff) {
    return *(const float*)(base + boff);
}

// block-level (sum,sumsq) reduction for OCPT channels -> partial store
template <int OCPT>
__device__ __forceinline__ void stats_block_store(
    const float* sv, const float* ssv, float* __restrict__ spart,
    float* __restrict__ sspart, int P, int tile, int pc0) {
    __shared__ float redS[OCPT], redSS[OCPT];
    if (threadIdx.x < OCPT) { redS[threadIdx.x] = 0.f; redSS[threadIdx.x] = 0.f; }
    __syncthreads();
    int lane = threadIdx.x & 63;
#pragma unroll
    for (int j = 0; j < OCPT; ++j) {
        float s = sv[j], ss = ssv[j];
#pragma unroll
        for (int o = 32; o > 0; o >>= 1) {
            s += __shfl_down(s, o);
            ss += __shfl_down(ss, o);
        }
        if (lane == 0) { atomicAdd(&redS[j], s); atomicAdd(&redSS[j], ss); }  // LDS atomics
    }
    __syncthreads();
    if (threadIdx.x < OCPT) {
        spart[(size_t)tile * P + pc0 + threadIdx.x] = redS[threadIdx.x];
        sspart[(size_t)tile * P + pc0 + threadIdx.x] = redSS[threadIdx.x];
    }
}

// fold [nT][P] partials -> mean, inv (one wavefront per plane)
__global__ __launch_bounds__(64) void stat_reduce_mi(
    const float* __restrict__ sp, const float* __restrict__ ssp,
    float* __restrict__ mean, float* __restrict__ inv, int P, int nT,
    float rcp_plane) {
    int p = blockIdx.x;
    float a = 0.f, bsum = 0.f;
    for (int t = threadIdx.x; t < nT; t += 64) {
        a += sp[(size_t)t * P + p];
        bsum += ssp[(size_t)t * P + p];
    }
#pragma unroll
    for (int o = 32; o > 0; o >>= 1) {
        a += __shfl_down(a, o);
        bsum += __shfl_down(bsum, o);
    }
    if (threadIdx.x == 0) {
        float m = a * rcp_plane;
        float var = bsum * rcp_plane - m * m;
        mean[p] = m;
        inv[p] = rsqrtf(var + 1e-5f);
    }
}

// ---------------- 7x7 same-conv (L0), LDS-staged tile, fused stats ----------
template <int CIN, int OCPT>
__global__ __launch_bounds__(256) void conv7_lds(
    const float* __restrict__ x, const float* __restrict__ w,
    const float* __restrict__ b, float* __restrict__ y,
    float* __restrict__ spart, float* __restrict__ sspart, int P,
    int Cout, int H, int W) {
    constexpr int TR = 22, TC = 22, RS = 24;
    __shared__ float s[CIN][TR][RS];
    int tx = threadIdx.x & 15, ty = threadIdx.x >> 4;
    int tilesX = W / 16;
    int bx = blockIdx.x % tilesX, by = blockIdx.x / tilesX;
    int oh0 = by * 16, ow0 = bx * 16;
    int oc0 = blockIdx.y * OCPT;
    int n = blockIdx.z;
    const float* xn = x + (size_t)n * CIN * H * W;

    for (int q = threadIdx.x; q < CIN * TR * TC; q += 256) {
        int p = q / (TR * TC), rem = q % (TR * TC);
        int r = rem / TC, c = rem % TC;
        int ih = reflect_i(oh0 + r - 3, H);
        int iw = reflect_i(ow0 + c - 3, W);
        s[p][r][c] = xn[(size_t)p * H * W + (size_t)ih * W + iw];
    }
    __syncthreads();

    float acc[OCPT];
#pragma unroll
    for (int j = 0; j < OCPT; ++j) acc[j] = 0.f;

    for (int ic = 0; ic < CIN; ++ic) {
        const float* wp = w + ((size_t)oc0 * CIN + ic) * 49;
#pragma unroll
        for (int kh = 0; kh < 7; ++kh) {
#pragma unroll
            for (int kw = 0; kw < 7; ++kw) {
                float vt = s[ic][ty + kh][tx + kw];
#pragma unroll
                for (int j = 0; j < OCPT; ++j)
                    acc[j] += vt * wp[(size_t)j * CIN * 49 + kh * 7 + kw];
            }
        }
    }

    int oh = oh0 + ty, ow = ow0 + tx;
    float sv[OCPT], ssv[OCPT];
#pragma unroll
    for (int j = 0; j < OCPT; ++j) {
        float r = acc[j] + b[oc0 + j];
        y[(((size_t)n * Cout + oc0 + j) * H + oh) * W + ow] = r;
        sv[j] = r;
        ssv[j] = r * r;
    }
    stats_block_store<OCPT>(sv, ssv, spart, sspart, P, blockIdx.x, n * Cout + oc0);
}

// ---------------- 7x7 conv, ic-split partial (L7), LDS-staged ---------------
template <int CINTOT, int ICPB, int OCPT>
__global__ __launch_bounds__(256) void conv7_part_lds(
    const float* __restrict__ x, const float* __restrict__ w,
    float* __restrict__ part, size_t PS, int H, int W) {
    constexpr int TR = 22, TC = 22, RS = 24;
    __shared__ float s[ICPB][TR][RS];
    int tx = threadIdx.x & 15, ty = threadIdx.x >> 4;
    int tilesX = IDIV(W, 16);
    int bx = blockIdx.x % tilesX, by = blockIdx.x / tilesX;
    int oh0 = by * 16, ow0 = bx * 16;
    int ks = blockIdx.y;
    int n = blockIdx.z;
    const int ic0 = ks * ICPB;
    const float* xn = x + (size_t)n * CINTOT * H * W;

    for (int q = threadIdx.x; q < ICPB * TR * TC; q += 256) {
        int p = q / (TR * TC), rem = q % (TR * TC);
        int r = rem / TC, c = rem % TC;
        int ih = reflect_i(oh0 + r - 3, H);
        int iw = reflect_i(ow0 + c - 3, W);
        s[p][r][c] = xn[(size_t)(ic0 + p) * H * W + (size_t)ih * W + iw];
    }
    __syncthreads();

    float acc[OCPT];
#pragma unroll
    for (int j = 0; j < OCPT; ++j) acc[j] = 0.f;

#pragma unroll
    for (int icl = 0; icl < ICPB; ++icl) {
        const float* wp = w + (size_t)(ic0 + icl) * 49;
#pragma unroll
        for (int kh = 0; kh < 7; ++kh) {
#pragma unroll
            for (int kw = 0; kw < 7; ++kw) {
                float vt = s[icl][ty + kh][tx + kw];
#pragma unroll
                for (int j = 0; j < OCPT; ++j)
                    acc[j] += vt * wp[(size_t)j * CINTOT * 49 + kh * 7 + kw];
            }
        }
    }

    int oh = oh0 + ty, ow = ow0 + tx;
    if (oh < H && ow < W) {
#pragma unroll
        for (int j = 0; j < OCPT; ++j)
            part[(size_t)ks * PS + (((size_t)n * OCPT + j) * H + oh) * W + ow] = acc[j];
    }
}

// ---------------- 3x3 s2 conv, float4 row loads, fused stats ----------------
// Each row of 3 taps = 3 consecutive floats -> one float4 (dword-aligned
// dwordx4; elem 3 unused). Left edge (iw0=-1) via clamped base + shift
// selects; right-edge over-read stays in allocated arena and is unused.
template <int CIN, int ICB, int OCPT>
__global__ __launch_bounds__(256) void conv3s2_f4(
    const float* __restrict__ x, const float* __restrict__ w,
    const float* __restrict__ b, float* __restrict__ y,
    float* __restrict__ spart, float* __restrict__ sspart, int P,
    int Cout, int Hin, int Win, int Hout, int Wout) {
    int tx = threadIdx.x & 15, ty = threadIdx.x >> 4;
    int tilesX = Wout >> 4;
    int ow = (blockIdx.x % tilesX) * 16 + tx;
    int oh = (blockIdx.x / tilesX) * 16 + ty;
    int oc0 = blockIdx.y * OCPT;
    int n = blockIdx.z;

    int iw0 = ow * 2 - 1;
    bool shb = iw0 < 0;                 // only ow==0 lanes
    int cb = shb ? 0 : iw0;             // clamped base col, in [0, Win-3]
    int ih0 = oh * 2 - 1;
    int rof[3];
    float mr[3];
#pragma unroll
    for (int kh = 0; kh < 3; ++kh) {
        int ih = ih0 + kh;
        int ihc = min(max(ih, 0), Hin - 1);
        rof[kh] = (ihc * Win + cb) * 4;
        mr[kh] = (ih >= 0 && ih < Hin) ? 1.f : 0.f;
    }

    float acc[OCPT];
#pragma unroll
    for (int j = 0; j < OCPT; ++j) acc[j] = 0.f;

    const char* xb = (const char*)x + (size_t)n * CIN * Hin * Win * 4;
    const int HWb = Hin * Win * 4;

    for (int ic0 = 0; ic0 < CIN; ic0 += ICB) {
        float t[ICB][9];
#pragma unroll
        for (int icl = 0; icl < ICB; ++icl) {
            const char* xp = xb + (size_t)(ic0 + icl) * HWb;  // uniform advance
#pragma unroll
            for (int kh = 0; kh < 3; ++kh) {
                float4 v = *(const float4*)(xp + rof[kh]);
                float e0 = shb ? 0.f : v.x;
                float e1 = shb ? v.x : v.y;
                float e2 = shb ? v.y : v.z;
                t[icl][kh * 3 + 0] = e0 * mr[kh];
                t[icl][kh * 3 + 1] = e1 * mr[kh];
                t[icl][kh * 3 + 2] = e2 * mr[kh];
            }
        }
#pragma unroll
        for (int icl = 0; icl < ICB; ++icl) {
            const float* wp = w + ((size_t)oc0 * CIN + ic0 + icl) * 9;
#pragma unroll
            for (int j = 0; j < OCPT; ++j) {
#pragma unroll
                for (int tt = 0; tt < 9; ++tt)
                    acc[j] += t[icl][tt] * wp[(size_t)j * CIN * 9 + tt];
            }
        }
    }
    float sv[OCPT], ssv[OCPT];
#pragma unroll
    for (int j = 0; j < OCPT; ++j) {
        float r = acc[j] + b[oc0 + j];
        y[(((size_t)n * Cout + oc0 + j) * Hout + oh) * Wout + ow] = r;
        sv[j] = r;
        ssv[j] = r * r;
    }
    stats_block_store<OCPT>(sv, ssv, spart, sspart, P, blockIdx.x, n * Cout + oc0);
}

// ---------------- 3x3 s2 transposed conv, quad, float2 loads, fused stats ---
// torch weight layout w[Cin][Cout][3][3]; output quad at (2qy,2qx).
// (p00,p01) and (p10,p11) are adjacent floats -> two float2 loads.
template <int CIN, int ICB, int OCPT>
__global__ __launch_bounds__(256) void convt3_v4s(
    const float* __restrict__ x, const float* __restrict__ w,
    const float* __restrict__ b, float* __restrict__ y,
    float* __restrict__ spart, float* __restrict__ sspart, int P,
    int Cout, int Hin, int Win, int Hout, int Wout) {
    int tx = threadIdx.x & 15, ty = threadIdx.x >> 4;
    int tilesX = IDIV(Win, 16);
    int qx = (blockIdx.x % tilesX) * 16 + tx;
    int qy = (blockIdx.x / tilesX) * 16 + ty;
    int oc0 = blockIdx.y * OCPT;
    int n = blockIdx.z;
    bool valid = (qx < Win) && (qy < Hin);
    int qxc = min(qx, Win - 1), qyc = min(qy, Hin - 1);
    bool xin = valid && (qx + 1 < Win), yin = valid && (qy + 1 < Hin);
    int o10 = yin ? Win : 0;
    float m01 = xin ? 1.f : 0.f, m10 = yin ? 1.f : 0.f, m11 = m01 * m10;

    int p00 = (qyc * Win + qxc) * 4;
    int p10 = p00 + o10 * 4;

    float a00[OCPT], a01[OCPT], a10[OCPT], a11[OCPT];
#pragma unroll
    for (int j = 0; j < OCPT; ++j) { a00[j] = a01[j] = a10[j] = a11[j] = 0.f; }

    const char* xb = (const char*)x + (size_t)n * CIN * Hin * Win * 4;  // uniform
    const int HWb = Hin * Win * 4;

    float va[ICB][4], vb[ICB][4];
    auto load = [&](float (&v)[ICB][4], int ic0) {
#pragma unroll
        for (int icl = 0; icl < ICB; ++icl) {
            const char* xp = xb + (size_t)(ic0 + icl) * HWb;  // uniform advance
            float2 u = *(const float2*)(xp + p00);
            float2 d = *(const float2*)(xp + p10);
            v[icl][0] = u.x;
            v[icl][1] = u.y * m01;
            v[icl][2] = d.x * m10;
            v[icl][3] = d.y * m11;
        }
    };
    auto fma = [&](const float (&v)[ICB][4], int ic0) {
#pragma unroll
        for (int icl = 0; icl < ICB; ++icl) {
            const float* wp = w + ((size_t)(ic0 + icl) * Cout + oc0) * 9;
#pragma unroll
            for (int j = 0; j < OCPT; ++j) {
                const float* wj = wp + j * 9;
                float w0 = wj[0], w1 = wj[1], w2 = wj[2];
                float w3 = wj[3], w4 = wj[4], w5 = wj[5];
                float w6 = wj[6], w7 = wj[7], w8 = wj[8];
                a00[j] += w4 * v[icl][0];
                a01[j] += w5 * v[icl][0] + w3 * v[icl][1];
                a10[j] += w7 * v[icl][0] + w1 * v[icl][2];
                a11[j] += w8 * v[icl][0] + w6 * v[icl][1] + w2 * v[icl][2] + w0 * v[icl][3];
            }
        }
    };

    load(va, 0);
    for (int ic0 = 0; ic0 < CIN; ic0 += 2 * ICB) {
        load(vb, ic0 + ICB);
        fma(va, ic0);
        load(va, min(ic0 + 2 * ICB, CIN - ICB));
        fma(vb, ic0 + ICB);
    }

    int oh = 2 * qy, ow = 2 * qx;
    float sv[OCPT], ssv[OCPT];
#pragma unroll
    for (int j = 0; j < OCPT; ++j) {
        float s = 0.f, ss = 0.f;
        if (valid) {
            float bb = b[oc0 + j];
            float* yp = y + (((size_t)n * Cout + oc0 + j) * Hout + oh) * Wout + ow;
            float t00 = a00[j] + bb;
            yp[0] = t00; s += t00; ss += t00 * t00;
            if (xin) { float t = a01[j] + bb; yp[1] = t; s += t; ss += t * t; }
            if (yin) { float t = a10[j] + bb; yp[Wout] = t; s += t; ss += t * t; }
            if (xin && yin) { float t = a11[j] + bb; yp[Wout + 1] = t; s += t; ss += t * t; }
        }
        sv[j] = s; ssv[j] = ss;
    }
    stats_block_store<OCPT>(sv, ssv, spart, sspart, P, blockIdx.x, n * Cout + oc0);
}

// ---------------- inorm apply, float4 coalesced (plane % 4 == 0) ------------
__global__ void inorm_apply4(float* __restrict__ x, const float* __restrict__ mean,
                             const float* __restrict__ inv, int plane4) {
    int pc = blockIdx.y;
    int i = blockIdx.x * 256 + threadIdx.x;
    if (i >= plane4) return;
    float m = mean[pc], iv = inv[pc];
    float4* p = (float4*)(x + (size_t)pc * plane4 * 4);
    float4 v = p[i];
    v.x = fmaxf(0.f, (v.x - m) * iv);
    v.y = fmaxf(0.f, (v.y - m) * iv);
    v.z = fmaxf(0.f, (v.z - m) * iv);
    v.w = fmaxf(0.f, (v.w - m) * iv);
    p[i] = v;
}

// ---------------- inorm apply, 1 elem/thread coalesced (any plane) ----------
__global__ void inorm_apply1(float* __restrict__ x, const float* __restrict__ mean,
                             const float* __restrict__ inv, int plane) {
    int pc = blockIdx.y;
    int i = blockIdx.x * 256 + threadIdx.x;
    if (i >= plane) return;
    float m = mean[pc], iv = inv[pc];
    size_t idx = (size_t)pc * plane + i;
    x[idx] = fmaxf(0.f, (x[idx] - m) * iv);
}

// ---------------- segment mean (accum fused with L7 finalize) ---------------
__global__ void seg_zero(float* __restrict__ bins) {
    if (threadIdx.x < 128) bins[threadIdx.x] = 0.f;
}

// reads the 4 ic-split partials + bias, computes tanh inline; a7 never built.
__global__ void seg_accum_f(const float* __restrict__ part, const float* __restrict__ b,
                            const int* __restrict__ inst, float* __restrict__ bins,
                            int HW, size_t PS) {
    __shared__ float ls[128];  // 96 sums + 32 counts
    for (int i = threadIdx.x; i < 128; i += 256) ls[i] = 0.f;
    __syncthreads();
    int n = blockIdx.y;
    int i = blockIdx.x * 256 + threadIdx.x;
    if (i < HW) {
        int id = inst[(size_t)n * HW + i];
#pragma unroll
        for (int c = 0; c < 3; ++c) {
            size_t off = ((size_t)(n * 3 + c)) * HW + i;
            float v = part[off] + part[PS + off] + part[2 * PS + off] +
                      part[3 * PS + off] + b[c];
            atomicAdd(&ls[id * 3 + c], tanhf(v));
        }
        atomicAdd(&ls[96 + id], 1.0f);
    }
    __syncthreads();
    for (int i2 = threadIdx.x; i2 < 128; i2 += 256)
        if (ls[i2] != 0.f) atomicAdd(&bins[i2], ls[i2]);
}

__global__ void seg_scatter(const float* __restrict__ bins, const int* __restrict__ inst,
                            float* __restrict__ out, int HW) {
    int n = blockIdx.y;
    int i = blockIdx.x * 256 + threadIdx.x;
    if (i >= HW) return;
    int id = inst[(size_t)n * HW + i];
    float c = fmaxf(bins[96 + id], 1.0f);
    out[((size_t)n * 3 + 0) * HW + i] = bins[id * 3 + 0] / c;
    out[((size_t)n * 3 + 1) * HW + i] = bins[id * 3 + 1] / c;
    out[((size_t)n * 3 + 2) * HW + i] = bins[id * 3 + 2] / c;
}

// ---------------------------------------------------------------------------
extern "C" void kernel_launch(void* const* d_in, const int* in_sizes, int n_in,
                              void* d_out, int out_size, void* d_ws, size_t ws_size,
                              hipStream_t stream) {
    const float* x = (const float*)d_in[0];
    const int* inst = (const int*)d_in[1];
    const float* W[8];
    const float* B[8];
    for (int i = 0; i < 8; ++i) {
        W[i] = (const float*)d_in[2 + 2 * i];
        B[i] = (const float*)d_in[3 + 2 * i];
    }
    float* ws = (float*)d_ws;

    // End-aligned ping-pong arena (R2/R6 proven)
    const size_t S = 25165824;  // floats
    float* a0 = ws;                  // [8,32,256,256]
    float* a1 = ws + 16777216;       // [8,64,128,128]
    float* a2 = ws;                  // [8,128,64,64]
    float* a3 = ws + 23068672;       // [8,256,32,32]
    float* a4 = ws;                  // [8,128,63,63]
    float* a5 = ws + 17165824;       // [8,64,125,125]
    float* a6 = ws;                  // [8,32,249,249]  0 .. 15.87M
    float* PART = ws + 16000000;     // 4 x 1488024 floats (gap above a6)
    float* mean = ws + S;            // 2048
    float* inv = mean + 2048;        // 2048
    float* bins = inv + 2048;        // 128
    float* spart = bins + 128;       // 65536 (max nT*P = 256*256)
    float* sspart = spart + 65536;   // 65536

    // L0: 7x7 reflect, 3->32, 256. LDS-staged, OCPT=8, 8192 blocks
    conv7_lds<3, 8><<<dim3(256, 4, 8), 256, 0, stream>>>(
        x, W[0], B[0], a0, spart, sspart, 256, 32, 256, 256);
    stat_reduce_mi<<<dim3(256), 64, 0, stream>>>(spart, sspart, mean, inv, 256, 256, 1.f / 65536.f);
    inorm_apply4<<<dim3(IDIV(16384, 256), 256), 256, 0, stream>>>(a0, mean, inv, 16384);

    // L1: 3x3 s2, 32->64, 256->128. float4 rows, ICB=2, OCPT=8, 4096 blocks
    conv3s2_f4<32, 2, 8><<<dim3(64, 8, 8), 256, 0, stream>>>(
        a0, W[1], B[1], a1, spart, sspart, 512, 64, 256, 256, 128, 128);
    stat_reduce_mi<<<dim3(512), 64, 0, stream>>>(spart, sspart, mean, inv, 512, 64, 1.f / 16384.f);
    inorm_apply4<<<dim3(IDIV(4096, 256), 512), 256, 0, stream>>>(a1, mean, inv, 4096);

    // L2: 3x3 s2, 64->128, 128->64. float4 rows, 2048 blocks
    conv3s2_f4<64, 2, 8><<<dim3(16, 16, 8), 256, 0, stream>>>(
        a1, W[2], B[2], a2, spart, sspart, 1024, 128, 128, 128, 64, 64);
    stat_reduce_mi<<<dim3(1024), 64, 0, stream>>>(spart, sspart, mean, inv, 1024, 16, 1.f / 4096.f);
    inorm_apply4<<<dim3(IDIV(1024, 256), 1024), 256, 0, stream>>>(a2, mean, inv, 1024);

    // L3: 3x3 s2, 128->256, 64->32. float4 rows, 1024 blocks
    conv3s2_f4<128, 2, 8><<<dim3(4, 32, 8), 256, 0, stream>>>(
        a2, W[3], B[3], a3, spart, sspart, 2048, 256, 64, 64, 32, 32);
    stat_reduce_mi<<<dim3(2048), 64, 0, stream>>>(spart, sspart, mean, inv, 2048, 4, 1.f / 1024.f);
    inorm_apply4<<<dim3(1, 2048), 256, 0, stream>>>(a3, mean, inv, 256);

    // L4: convT, 256->128, 32->63. float2 loads, OCPT=4
    convt3_v4s<256, 4, 4><<<dim3(4, 32, 8), 256, 0, stream>>>(
        a3, W[4], B[4], a4, spart, sspart, 1024, 128, 32, 32, 63, 63);
    stat_reduce_mi<<<dim3(1024), 64, 0, stream>>>(spart, sspart, mean, inv, 1024, 4, 1.f / 3969.f);
    inorm_apply1<<<dim3(IDIV(3969, 256), 1024), 256, 0, stream>>>(a4, mean, inv, 3969);

    // L5: convT, 128->64, 63->125. float2 loads, OCPT=4, 2048 blocks
    convt3_v4s<128, 4, 4><<<dim3(16, 16, 8), 256, 0, stream>>>(
        a4, W[5], B[5], a5, spart, sspart, 512, 64, 63, 63, 125, 125);
    stat_reduce_mi<<<dim3(512), 64, 0, stream>>>(spart, sspart, mean, inv, 512, 16, 1.f / 15625.f);
    inorm_apply1<<<dim3(IDIV(15625, 256), 512), 256, 0, stream>>>(a5, mean, inv, 15625);

    // L6: convT, 64->32, 125->249. float2 loads, OCPT=4, 4096 blocks
    convt3_v4s<64, 4, 4><<<dim3(64, 8, 8), 256, 0, stream>>>(
        a5, W[6], B[6], a6, spart, sspart, 256, 32, 125, 125, 249, 249);
    stat_reduce_mi<<<dim3(256), 64, 0, stream>>>(spart, sspart, mean, inv, 256, 64, 1.f / 62001.f);
    inorm_apply1<<<dim3(IDIV(62001, 256), 256), 256, 0, stream>>>(a6, mean, inv, 62001);

    // L7: 7x7 reflect, 32->3, 249 — ic-split x4, LDS-staged
    conv7_part_lds<32, 8, 3><<<dim3(256, 4, 8), 256, 0, stream>>>(
        a6, W[7], PART, 1488024, 249, 249);

    // segment mean (accum reads partials + bias + tanh inline)
    seg_zero<<<1, 128, 0, stream>>>(bins);
    seg_accum_f<<<dim3(IDIV(62001, 256), 8), 256, 0, stream>>>(
        PART, B[7], inst, bins, 62001, 1488024);
    seg_scatter<<<dim3(IDIV(62001, 256), 8), 256, 0, stream>>>(bins, inst, (float*)d_out, 62001);
}